// Round 2
// baseline (353.198 us; speedup 1.0000x reference)
//
#include <hip/hip_runtime.h>

// TorchPatchNN: unfold(7x7) -> NN argmin over 8100 keys (D=147) -> gather value -> fold mean.
// Round 2: same structure as R1, but fp32 I/O (reference dtype; R1's bf16 misread caused NaN).

#define NQ 8100
#define NK 8100
#define DD 147
#define QS 8192      // padded column stride for transposed mats
#define DP 148       // padded D rows
#define HO 90
#define IMG 96
#define TQ 128
#define TK 128
#define KSPLIT 8
#define KRANGE 1024  // keys per split (8 tiles of 128)

// ---------------- prep: unfold query into q2dT[d][q] (f32) ----------------
__global__ void k_unfold(const float* __restrict__ query, float* __restrict__ q2dT) {
    int t = blockIdx.x * 256 + threadIdx.x;   // over DP*QS
    int d = t >> 13;
    int q = t & 8191;
    float v = 0.f;
    if (d < DD && q < NQ) {
        int c = d / 49, r = (d % 49) / 7, s = d % 7;
        int y = q / HO, x = q % HO;
        v = query[(c * IMG + y + r) * IMG + x + s];
    }
    q2dT[t] = v;
}

// ---------------- prep: transpose key into kT[d][k] (f32) ----------------
__global__ void k_keyT(const float* __restrict__ key, float* __restrict__ kT) {
    int t = blockIdx.x * 256 + threadIdx.x;   // over DP*QS
    int d = t >> 13;
    int k = t & 8191;
    float v = 0.f;
    if (d < DD && k < NK) v = key[k * DD + d];
    kT[t] = v;
}

// ---------------- prep: key squared norms (padded keys get +inf-ish) ----------------
__global__ void k_kn(const float* __restrict__ key, float* __restrict__ kn) {
    int k = blockIdx.x * 4 + (threadIdx.x >> 6);   // one wave per key
    int lane = threadIdx.x & 63;
    float s = 0.f;
    if (k < NK) {
        for (int d = lane; d < DD; d += 64) {
            float v = key[k * DD + d];
            s += v * v;
        }
    }
#pragma unroll
    for (int off = 32; off; off >>= 1) s += __shfl_down(s, off, 64);
    if (lane == 0) kn[k] = (k < NK) ? s : 1e30f;
}

// ---------------- main: fused Q.K^T + row argmin of (kn - 2 q.k) ----------------
__launch_bounds__(256, 3)
__global__ void k_nn(const float* __restrict__ q2dT, const float* __restrict__ kT,
                     const float* __restrict__ kn,
                     float* __restrict__ bval, int* __restrict__ bidx) {
    __shared__ __align__(16) float qs_[49 * 128];
    __shared__ __align__(16) float ks_[49 * 128];

    const int sp = blockIdx.x;     // key split 0..7
    const int qt = blockIdx.y;     // query tile 0..63
    const int tid = (int)threadIdx.x;
    const int tx = tid & 15;       // key micro-tile (8 keys)
    const int ty = tid >> 4;       // query micro-tile (8 queries)
    const int q0 = qt * TQ;
    const int ks0 = sp * KRANGE;

    float best[8];
    int bi[8];
#pragma unroll
    for (int i = 0; i < 8; ++i) { best[i] = 1e30f; bi[i] = 0; }

    for (int kt = 0; kt < KRANGE / TK; ++kt) {
        float acc[8][8];
#pragma unroll
        for (int i = 0; i < 8; ++i)
#pragma unroll
            for (int j = 0; j < 8; ++j) acc[i][j] = 0.f;

        for (int c3 = 0; c3 < 3; ++c3) {
            __syncthreads();
            // stage 49 x 128 chunks of Q and K (both already [d][col] in global)
            for (int it = tid; it < 49 * 32; it += 256) {
                int row = it >> 5;
                int c4 = (it & 31) << 2;
                int grow = c3 * 49 + row;
                *(float4*)&qs_[row * 128 + c4] =
                    *(const float4*)&q2dT[grow * QS + q0 + c4];
                *(float4*)&ks_[row * 128 + c4] =
                    *(const float4*)&kT[grow * QS + ks0 + kt * 128 + c4];
            }
            __syncthreads();

#pragma unroll 7
            for (int d = 0; d < 49; ++d) {
                float qa[8], ka[8];
                float4 t0 = *(const float4*)&qs_[d * 128 + ty * 8];
                float4 t1 = *(const float4*)&qs_[d * 128 + ty * 8 + 4];
                float4 t2 = *(const float4*)&ks_[d * 128 + tx * 8];
                float4 t3 = *(const float4*)&ks_[d * 128 + tx * 8 + 4];
                qa[0] = t0.x; qa[1] = t0.y; qa[2] = t0.z; qa[3] = t0.w;
                qa[4] = t1.x; qa[5] = t1.y; qa[6] = t1.z; qa[7] = t1.w;
                ka[0] = t2.x; ka[1] = t2.y; ka[2] = t2.z; ka[3] = t2.w;
                ka[4] = t3.x; ka[5] = t3.y; ka[6] = t3.z; ka[7] = t3.w;
#pragma unroll
                for (int i = 0; i < 8; ++i)
#pragma unroll
                    for (int j = 0; j < 8; ++j) acc[i][j] += qa[i] * ka[j];
            }
        }

        // fold in kn, update running argmin (ascending key index + strict < ==
        // first-occurrence argmin semantics)
        const int kbase = ks0 + kt * 128 + tx * 8;
#pragma unroll
        for (int j = 0; j < 8; ++j) {
            float knj = kn[kbase + j];
#pragma unroll
            for (int i = 0; i < 8; ++i) {
                float dm = knj - 2.f * acc[i][j];
                if (dm < best[i]) { best[i] = dm; bi[i] = kbase + j; }
            }
        }
    }

    // reduce across the 16 tx lanes sharing each query row
    __syncthreads();
    float* redv = qs_;            // 128*16 floats
    int* redi = (int*)ks_;        // 128*16 ints
#pragma unroll
    for (int i = 0; i < 8; ++i) {
        redv[(ty * 8 + i) * 16 + tx] = best[i];
        redi[(ty * 8 + i) * 16 + tx] = bi[i];
    }
    __syncthreads();
    if (tid < 128) {
        float bv = 1e30f;
        int bb = 0;
        for (int t = 0; t < 16; ++t) {   // ascending tx == ascending key idx
            float v = redv[tid * 16 + t];
            if (v < bv) { bv = v; bb = redi[tid * 16 + t]; }
        }
        bval[sp * QS + q0 + tid] = bv;
        bidx[sp * QS + q0 + tid] = bb;
    }
}

// ---------------- combine splits ----------------
__global__ void k_combine(const float* __restrict__ bval, const int* __restrict__ bidx,
                          int* __restrict__ fidx) {
    int q = blockIdx.x * 256 + threadIdx.x;   // 8192
    float bv = 1e30f;
    int bb = 0;
    for (int sp = 0; sp < KSPLIT; ++sp) {     // ascending sp == ascending key idx
        float v = bval[sp * QS + q];
        if (v < bv) { bv = v; bb = bidx[sp * QS + q]; }
    }
    fidx[q] = bb;
}

// ---------------- gather + fold (overlap-add mean) ----------------
__global__ void k_fold(const float* __restrict__ value, const int* __restrict__ fidx,
                       float* __restrict__ out) {
    int t = blockIdx.x * 256 + threadIdx.x;   // 3*96*96 = 27648
    if (t >= 3 * IMG * IMG) return;
    int c = t / (IMG * IMG);
    int rem = t % (IMG * IMG);
    int Y = rem / IMG, X = rem % IMG;
    int i0 = max(0, Y - (HO - 1)), i1 = min(6, Y);
    int j0 = max(0, X - (HO - 1)), j1 = min(6, X);
    float s = 0.f;
    for (int i = i0; i <= i1; ++i)
        for (int j = j0; j <= j1; ++j) {
            int p = (Y - i) * HO + (X - j);
            int row = fidx[p];
            s += value[row * DD + c * 49 + i * 7 + j];
        }
    float cnt = (float)((i1 - i0 + 1) * (j1 - j0 + 1));
    out[t] = s / cnt;
}

extern "C" void kernel_launch(void* const* d_in, const int* in_sizes, int n_in,
                              void* d_out, int out_size, void* d_ws, size_t ws_size,
                              hipStream_t stream) {
    const float* query = (const float*)d_in[0];
    const float* key   = (const float*)d_in[1];
    const float* value = (const float*)d_in[2];
    float* out = (float*)d_out;

    float* q2dT = (float*)d_ws;               // DP*QS
    float* kT   = q2dT + DP * QS;             // DP*QS
    float* kn   = kT + DP * QS;               // QS
    float* bval = kn + QS;                    // KSPLIT*QS
    int*   bidx = (int*)(bval + KSPLIT * QS); // KSPLIT*QS
    int*   fidx = bidx + KSPLIT * QS;         // QS

    k_unfold<<<DP * QS / 256, 256, 0, stream>>>(query, q2dT);
    k_keyT<<<DP * QS / 256, 256, 0, stream>>>(key, kT);
    k_kn<<<2048, 256, 0, stream>>>(key, kn);
    dim3 g(KSPLIT, 64);
    k_nn<<<g, 256, 0, stream>>>(q2dT, kT, kn, bval, bidx);
    k_combine<<<32, 256, 0, stream>>>(bval, bidx, fidx);
    k_fold<<<108, 256, 0, stream>>>(value, fidx, out);
}

// Round 3
// 228.031 us; speedup vs baseline: 1.5489x; 1.5489x over previous
//
#include <hip/hip_runtime.h>

// TorchPatchNN: unfold(7x7) -> NN argmin over 8100 keys (D=147) -> gather value -> fold mean.
// Round 3: MFMA path. fp16 2-term split (h + 2^-11 * l'), 3 MFMA passes into 2 accumulator
// groups -> dot error ~3e-5 (below fp32-GEMM noise; R2 showed argmin gaps >~1e-3).
// Cross-block argmin via packed u64 atomicMin (dist-order bits << 32 | key index).

#define NQ 8100
#define NK 8100
#define DD 147
#define HO 90
#define IMG 96
#define NCH 5            // K chunks of 32
#define KP 40            // padded chunk row: 32 data + 8 zero f16 (LDS conflict pad)
#define CSTR (8192 * KP) // f16 elems per chunk plane
#define ARRN (NCH * CSTR)

typedef _Float16 half8 __attribute__((ext_vector_type(8)));
typedef float f32x4 __attribute__((ext_vector_type(4)));

// ---------------- prep: unfold query + fp16 hi/lo split into chunked layout ----------------
__global__ void k_split_q(const float* __restrict__ q, _Float16* __restrict__ Qh,
                          _Float16* __restrict__ Ql) {
    int t = blockIdx.x * 256 + threadIdx.x;      // over ARRN = 1,638,400
    int c = t / CSTR;
    int rem = t - c * CSTR;
    int col = rem / KP;
    int j = rem - col * KP;
    int k = c * 32 + j;
    float v = 0.f;
    if (j < 32 && k < DD && col < NQ) {
        int c3 = k / 49, rr = (k % 49) / 7, ss = k % 7;
        int y = col / HO, x = col - y * HO;
        v = q[(c3 * IMG + y + rr) * IMG + x + ss];
    }
    _Float16 h = (_Float16)v;
    _Float16 l = (_Float16)((v - (float)h) * 2048.0f);
    Qh[t] = h;
    Ql[t] = l;
}

// ---------------- prep: key fp16 hi/lo split ----------------
__global__ void k_split_k(const float* __restrict__ key, _Float16* __restrict__ Kh,
                          _Float16* __restrict__ Kl) {
    int t = blockIdx.x * 256 + threadIdx.x;
    int c = t / CSTR;
    int rem = t - c * CSTR;
    int col = rem / KP;
    int j = rem - col * KP;
    int k = c * 32 + j;
    float v = 0.f;
    if (j < 32 && k < DD && col < NK) v = key[col * DD + k];
    _Float16 h = (_Float16)v;
    _Float16 l = (_Float16)((v - (float)h) * 2048.0f);
    Kh[t] = h;
    Kl[t] = l;
}

// ---------------- prep: key squared norms + argmin sentinel init ----------------
__global__ void k_kn(const float* __restrict__ key, float* __restrict__ kn,
                     unsigned long long* __restrict__ fidx64) {
    int k = blockIdx.x * 4 + (threadIdx.x >> 6);   // one wave per key, 8192 total
    int lane = threadIdx.x & 63;
    float s = 0.f;
    if (k < NK) {
        for (int d = lane; d < DD; d += 64) {
            float v = key[k * DD + d];
            s += v * v;
        }
    }
#pragma unroll
    for (int off = 32; off; off >>= 1) s += __shfl_down(s, off, 64);
    if (lane == 0) {
        kn[k] = (k < NK) ? s : 1e30f;
        fidx64[k] = 0xFFFFFFFFFFFFFFFFull;   // re-init every launch (ws is re-poisoned)
    }
}

// ---------------- main: split-f16 MFMA Q.K^T + fused argmin ----------------
__launch_bounds__(256, 2)
__global__ void k_nn(const _Float16* __restrict__ Qh, const _Float16* __restrict__ Ql,
                     const _Float16* __restrict__ Kh, const _Float16* __restrict__ Kl,
                     const float* __restrict__ kn, unsigned long long* __restrict__ out) {
    __shared__ __align__(16) char smem[40960];
    _Float16* sQh = (_Float16*)smem;              // 128 rows x 40 f16 = 10240 B each
    _Float16* sQl = (_Float16*)(smem + 10240);
    _Float16* sKh = (_Float16*)(smem + 20480);
    _Float16* sKl = (_Float16*)(smem + 30720);

    const int kt = blockIdx.x, qt = blockIdx.y;
    const int tid = (int)threadIdx.x;
    const int wave = tid >> 6, lane = tid & 63;
    const int l15 = lane & 15, quad = lane >> 4;
    const int mbase = (wave >> 1) * 64;           // wave tile: 64x64 within 128x128
    const int nbase = (wave & 1) * 64;
    const int q0 = qt * 128, n0 = kt * 128;

    f32x4 acc0[4][4], acc1[4][4];
#pragma unroll
    for (int i = 0; i < 4; ++i)
#pragma unroll
        for (int j = 0; j < 4; ++j) {
            acc0[i][j] = (f32x4)0.f;
            acc1[i][j] = (f32x4)0.f;
        }

    for (int c = 0; c < NCH; ++c) {
        __syncthreads();
        // stage 4 arrays x (128 rows x 40 f16) = 4 x 640 float4
        const int gQ = c * CSTR + q0 * KP;
        const int gK = c * CSTR + n0 * KP;
        for (int u = tid; u < 640; u += 256) {
            ((float4*)sQh)[u] = ((const float4*)(Qh + gQ))[u];
            ((float4*)sQl)[u] = ((const float4*)(Ql + gQ))[u];
            ((float4*)sKh)[u] = ((const float4*)(Kh + gK))[u];
            ((float4*)sKl)[u] = ((const float4*)(Kl + gK))[u];
        }
        __syncthreads();

        half8 ah[4], al[4];
#pragma unroll
        for (int mt = 0; mt < 4; ++mt) {
            int aoff = (mbase + mt * 16 + l15) * KP + quad * 8;
            ah[mt] = *(const half8*)(sQh + aoff);
            al[mt] = *(const half8*)(sQl + aoff);
        }
#pragma unroll
        for (int nt = 0; nt < 4; ++nt) {
            int boff = (nbase + nt * 16 + l15) * KP + quad * 8;
            half8 bh = *(const half8*)(sKh + boff);
            half8 bl = *(const half8*)(sKl + boff);
#pragma unroll
            for (int mt = 0; mt < 4; ++mt) {
                acc0[mt][nt] = __builtin_amdgcn_mfma_f32_16x16x32_f16(ah[mt], bh, acc0[mt][nt], 0, 0, 0);
                acc1[mt][nt] = __builtin_amdgcn_mfma_f32_16x16x32_f16(ah[mt], bl, acc1[mt][nt], 0, 0, 0);
                acc1[mt][nt] = __builtin_amdgcn_mfma_f32_16x16x32_f16(al[mt], bh, acc1[mt][nt], 0, 0, 0);
            }
        }
    }

    // epilogue: dist = kn - 2*(acc0 + acc1/2048); per-lane argmin over its 4 columns
    float knv[4];
    int nglob[4];
#pragma unroll
    for (int nt = 0; nt < 4; ++nt) {
        nglob[nt] = n0 + nbase + nt * 16 + l15;
        knv[nt] = kn[nglob[nt]];
    }
    __syncthreads();   // done with staging LDS; reuse for reduction
    float* redv = (float*)smem;           // [128][32]
    int* redi = (int*)(smem + 16384);     // [128][32]

#pragma unroll
    for (int mt = 0; mt < 4; ++mt)
#pragma unroll
        for (int r = 0; r < 4; ++r) {
            float bv = 1e38f;
            int bn = 0x7fffffff;
#pragma unroll
            for (int nt = 0; nt < 4; ++nt) {   // ascending n within lane -> strict < ok
                float d = knv[nt] - 2.0f * (acc0[mt][nt][r] + acc1[mt][nt][r] * (1.0f / 2048.0f));
                if (d < bv) { bv = d; bn = nglob[nt]; }
            }
            int m = mbase + mt * 16 + quad * 4 + r;        // C layout: row = quad*4 + reg
            int cidx = (nbase >> 2) + l15;                  // 0..31 (two n-half waves)
            redv[m * 32 + cidx] = bv;
            redi[m * 32 + cidx] = bn;
        }
    __syncthreads();

    if (tid < 128) {
        float bv = 1e38f;
        int bn = 0x7fffffff;
        for (int t2 = 0; t2 < 32; ++t2) {     // lanes interleave n -> tie-aware compare
            float v = redv[tid * 32 + t2];
            int n = redi[tid * 32 + t2];
            if (v < bv || (v == bv && n < bn)) { bv = v; bn = n; }
        }
        unsigned u = __float_as_uint(bv);
        u = (u & 0x80000000u) ? ~u : (u | 0x80000000u);   // order-preserving map
        unsigned long long pk = ((unsigned long long)u << 32) | (unsigned)bn;
        atomicMin(&out[q0 + tid], pk);
    }
}

// ---------------- gather + fold (overlap-add mean) ----------------
__global__ void k_fold(const float* __restrict__ value,
                       const unsigned long long* __restrict__ fidx64,
                       float* __restrict__ out) {
    int t = blockIdx.x * 256 + threadIdx.x;   // 3*96*96 = 27648
    if (t >= 3 * IMG * IMG) return;
    int c = t / (IMG * IMG);
    int rem = t % (IMG * IMG);
    int Y = rem / IMG, X = rem % IMG;
    int i0 = max(0, Y - (HO - 1)), i1 = min(6, Y);
    int j0 = max(0, X - (HO - 1)), j1 = min(6, X);
    float s = 0.f;
    for (int i = i0; i <= i1; ++i)
        for (int j = j0; j <= j1; ++j) {
            int p = (Y - i) * HO + (X - j);
            int row = (int)(fidx64[p] & 0xFFFFFFFFull);
            s += value[row * DD + c * 49 + i * 7 + j];
        }
    float cnt = (float)((i1 - i0 + 1) * (j1 - j0 + 1));
    out[t] = s / cnt;
}

extern "C" void kernel_launch(void* const* d_in, const int* in_sizes, int n_in,
                              void* d_out, int out_size, void* d_ws, size_t ws_size,
                              hipStream_t stream) {
    const float* query = (const float*)d_in[0];
    const float* key   = (const float*)d_in[1];
    const float* value = (const float*)d_in[2];
    float* out = (float*)d_out;

    _Float16* Qh = (_Float16*)d_ws;           // ARRN each
    _Float16* Ql = Qh + ARRN;
    _Float16* Kh = Ql + ARRN;
    _Float16* Kl = Kh + ARRN;
    float* kn = (float*)(Kl + ARRN);          // 8192 f32
    unsigned long long* fidx64 = (unsigned long long*)(kn + 8192);   // 8192 u64

    k_split_q<<<ARRN / 256, 256, 0, stream>>>(query, Qh, Ql);
    k_split_k<<<ARRN / 256, 256, 0, stream>>>(key, Kh, Kl);
    k_kn<<<2048, 256, 0, stream>>>(key, kn, fidx64);
    dim3 g(64, 64);
    k_nn<<<g, 256, 0, stream>>>(Qh, Ql, Kh, Kl, kn, fidx64);
    k_fold<<<108, 256, 0, stream>>>(value, fidx64, out);
}

// Round 4
// 203.504 us; speedup vs baseline: 1.7356x; 1.1205x over previous
//
#include <hip/hip_runtime.h>

// TorchPatchNN: unfold(7x7) -> NN argmin over 8100 keys (D=147) -> gather value -> fold mean.
// Round 4: fragment-order operand layout + global_load_lds staging (m97 pattern).
//  - Global layout per array: [chunk c][group g][lane][8 f16], addr = c*262144 + g*512 + lane*8.
//    Lane l = quad*16+l15 holds (col = g*16+l15, k = c*32+quad*8+j) == MFMA A/B frag order.
//  - LDS reads become lane-contiguous ds_read_b128 (conflict-free); staging is
//    global_load_lds dwordx4, 1 KiB/wave/instruction, no LDS write phase.
//  - Numerics unchanged from R3 (fp16 h + 2^-11*l split, 3 MFMAs, dual acc): absmax was 0.

#define NQ 8100
#define NK 8100
#define DD 147
#define HO 90
#define IMG 96
#define NCH 5                 // K chunks of 32 (160 padded K)
#define CST 262144            // f16 per chunk plane: 512 groups x 512
#define ARRN (NCH * CST)      // f16 per array

typedef _Float16 half8 __attribute__((ext_vector_type(8)));
typedef float f32x4 __attribute__((ext_vector_type(4)));

__device__ __forceinline__ void gld16(const _Float16* g, _Float16* l) {
    __builtin_amdgcn_global_load_lds(
        (const __attribute__((address_space(1))) unsigned int*)g,
        (__attribute__((address_space(3))) unsigned int*)l, 16, 0, 0);
}

// ---------------- prep: split Q (unfolded) and K into fp16 hi/lo, fragment order ----------
__global__ void k_prep(const float* __restrict__ query, const float* __restrict__ key,
                       _Float16* __restrict__ Qh, _Float16* __restrict__ Ql,
                       _Float16* __restrict__ Kh, _Float16* __restrict__ Kl) {
    int t = blockIdx.x * 256 + threadIdx.x;     // 0 .. 163839 (ARRN/8)
    const bool isK = (blockIdx.y != 0);
    int c = t >> 15;                            // chunk
    int rem = t & 32767;                        // g*64 + lane
    int col = ((rem >> 6) << 4) + (rem & 15);   // g*16 + l15
    int quad = (rem >> 4) & 3;
    int kbase = c * 32 + quad * 8;

    float v[8];
#pragma unroll
    for (int j = 0; j < 8; ++j) {
        int k = kbase + j;
        float x = 0.f;
        if (k < DD && col < NQ) {
            if (isK) {
                x = key[col * DD + k];
            } else {
                int c3 = k / 49, r2 = k - 49 * c3;
                int rr = r2 / 7, ss = r2 - 7 * rr;
                int y = col / HO, xx = col - HO * y;
                x = query[(c3 * IMG + y + rr) * IMG + xx + ss];
            }
        }
        v[j] = x;
    }
    half8 h8, l8;
#pragma unroll
    for (int j = 0; j < 8; ++j) {
        _Float16 h = (_Float16)v[j];
        h8[j] = h;
        l8[j] = (_Float16)((v[j] - (float)h) * 2048.0f);
    }
    if (isK) {
        *(half8*)(Kh + t * 8) = h8;
        *(half8*)(Kl + t * 8) = l8;
    } else {
        *(half8*)(Qh + t * 8) = h8;
        *(half8*)(Ql + t * 8) = l8;
    }
}

// ---------------- prep: key squared norms + argmin sentinel init ----------------
__global__ void k_kn(const float* __restrict__ key, float* __restrict__ kn,
                     unsigned long long* __restrict__ fidx64) {
    int k = blockIdx.x * 4 + (threadIdx.x >> 6);   // one wave per key, 8192 total
    int lane = threadIdx.x & 63;
    float s = 0.f;
    if (k < NK) {
        for (int d = lane; d < DD; d += 64) {
            float v = key[k * DD + d];
            s += v * v;
        }
    }
#pragma unroll
    for (int off = 32; off; off >>= 1) s += __shfl_down(s, off, 64);
    if (lane == 0) {
        kn[k] = (k < NK) ? s : 1e30f;
        fidx64[k] = 0xFFFFFFFFFFFFFFFFull;   // ws re-poisoned every launch
    }
}

// ---------------- main: split-f16 MFMA Q.K^T + fused argmin ----------------
__launch_bounds__(256, 2)
__global__ void k_nn(const _Float16* __restrict__ Qh, const _Float16* __restrict__ Ql,
                     const _Float16* __restrict__ Kh, const _Float16* __restrict__ Kl,
                     const float* __restrict__ kn, unsigned long long* __restrict__ out) {
    __shared__ __align__(16) char smemc[32768];
    _Float16* sAll = (_Float16*)smemc;   // 4 arrays x 8 groups x 512 f16 (8 KiB each)

    const int kt = blockIdx.x, qt = blockIdx.y;
    const int tid = (int)threadIdx.x;
    const int wave = tid >> 6, lane = tid & 63;
    const int l15 = lane & 15, quad = lane >> 4;
    const int mbase = (wave >> 1) * 64;           // wave tile: 64x64 within 128x128
    const int nbase = (wave & 1) * 64;
    const int q0 = qt * 128, n0 = kt * 128;

    // per-wave staging source: wave 0->Qh,1->Ql,2->Kh,3->Kl
    const _Float16* gsrc = (wave == 0) ? Qh : (wave == 1) ? Ql : (wave == 2) ? Kh : Kl;
    const int gbase = (wave < 2) ? qt * 8 : kt * 8;
    const _Float16* gp0 = gsrc + gbase * 512 + lane * 8;
    _Float16* ldst = sAll + wave * 4096 + lane * 8;

    f32x4 acc0[4][4], acc1[4][4];
#pragma unroll
    for (int i = 0; i < 4; ++i)
#pragma unroll
        for (int j = 0; j < 4; ++j) {
            acc0[i][j] = (f32x4)0.f;
            acc1[i][j] = (f32x4)0.f;
        }

    const _Float16* sQh = sAll;
    const _Float16* sQl = sAll + 4096;
    const _Float16* sKh = sAll + 8192;
    const _Float16* sKl = sAll + 12288;
    const int agrp = (mbase >> 4);
    const int bgrp = (nbase >> 4);

    for (int c = 0; c < NCH; ++c) {
        __syncthreads();
        const _Float16* gp = gp0 + c * CST;
#pragma unroll
        for (int grp = 0; grp < 8; ++grp)
            gld16(gp + grp * 512, ldst + grp * 512);
        __syncthreads();   // compiler drains vmcnt before s_barrier

        half8 ah[4], al[4];
#pragma unroll
        for (int mt = 0; mt < 4; ++mt) {
            int aoff = (agrp + mt) * 512 + lane * 8;
            ah[mt] = *(const half8*)(sQh + aoff);
            al[mt] = *(const half8*)(sQl + aoff);
        }
#pragma unroll
        for (int nt = 0; nt < 4; ++nt) {
            int boff = (bgrp + nt) * 512 + lane * 8;
            half8 bh = *(const half8*)(sKh + boff);
            half8 bl = *(const half8*)(sKl + boff);
#pragma unroll
            for (int mt = 0; mt < 4; ++mt) {
                acc0[mt][nt] = __builtin_amdgcn_mfma_f32_16x16x32_f16(ah[mt], bh, acc0[mt][nt], 0, 0, 0);
                acc1[mt][nt] = __builtin_amdgcn_mfma_f32_16x16x32_f16(ah[mt], bl, acc1[mt][nt], 0, 0, 0);
                acc1[mt][nt] = __builtin_amdgcn_mfma_f32_16x16x32_f16(al[mt], bh, acc1[mt][nt], 0, 0, 0);
            }
        }
    }

    // epilogue: dist = kn - 2*(acc0 + acc1/2048); per-lane argmin over its 4 columns
    float knv[4];
    int nglob[4];
#pragma unroll
    for (int nt = 0; nt < 4; ++nt) {
        nglob[nt] = n0 + nbase + nt * 16 + l15;
        knv[nt] = kn[nglob[nt]];
    }
    __syncthreads();   // done with staging LDS; reuse for reduction
    float* redv = (float*)smemc;           // [128][32] f32 = 16 KiB
    int* redi = (int*)(smemc + 16384);     // [128][32] i32 = 16 KiB

#pragma unroll
    for (int mt = 0; mt < 4; ++mt)
#pragma unroll
        for (int r = 0; r < 4; ++r) {
            float bv = 1e38f;
            int bn = 0x7fffffff;
#pragma unroll
            for (int nt = 0; nt < 4; ++nt) {   // ascending n within lane -> strict < ok
                float d = knv[nt] - 2.0f * (acc0[mt][nt][r] + acc1[mt][nt][r] * (1.0f / 2048.0f));
                if (d < bv) { bv = d; bn = nglob[nt]; }
            }
            int m = mbase + mt * 16 + quad * 4 + r;        // C layout: row = quad*4 + reg
            int cidx = (nbase >> 2) + l15;                 // 0..31
            redv[m * 32 + cidx] = bv;
            redi[m * 32 + cidx] = bn;
        }
    __syncthreads();

    if (tid < 128) {
        float bv = 1e38f;
        int bn = 0x7fffffff;
        for (int t2 = 0; t2 < 32; ++t2) {     // lanes interleave n -> tie-aware compare
            float v = redv[tid * 32 + t2];
            int n = redi[tid * 32 + t2];
            if (v < bv || (v == bv && n < bn)) { bv = v; bn = n; }
        }
        unsigned u = __float_as_uint(bv);
        u = (u & 0x80000000u) ? ~u : (u | 0x80000000u);   // order-preserving map
        unsigned long long pk = ((unsigned long long)u << 32) | (unsigned)bn;
        atomicMin(&out[q0 + tid], pk);
    }
}

// ---------------- gather + fold (overlap-add mean) ----------------
__global__ void k_fold(const float* __restrict__ value,
                       const unsigned long long* __restrict__ fidx64,
                       float* __restrict__ out) {
    int t = blockIdx.x * 256 + threadIdx.x;   // 3*96*96 = 27648
    if (t >= 3 * IMG * IMG) return;
    int c = t / (IMG * IMG);
    int rem = t % (IMG * IMG);
    int Y = rem / IMG, X = rem % IMG;
    int i0 = max(0, Y - (HO - 1)), i1 = min(6, Y);
    int j0 = max(0, X - (HO - 1)), j1 = min(6, X);
    float s = 0.f;
    for (int i = i0; i <= i1; ++i)
        for (int j = j0; j <= j1; ++j) {
            int p = (Y - i) * HO + (X - j);
            int row = (int)(fidx64[p] & 0xFFFFFFFFull);
            s += value[row * DD + c * 49 + i * 7 + j];
        }
    float cnt = (float)((i1 - i0 + 1) * (j1 - j0 + 1));
    out[t] = s / cnt;
}

extern "C" void kernel_launch(void* const* d_in, const int* in_sizes, int n_in,
                              void* d_out, int out_size, void* d_ws, size_t ws_size,
                              hipStream_t stream) {
    const float* query = (const float*)d_in[0];
    const float* key   = (const float*)d_in[1];
    const float* value = (const float*)d_in[2];
    float* out = (float*)d_out;

    _Float16* Qh = (_Float16*)d_ws;           // ARRN f16 each
    _Float16* Ql = Qh + ARRN;
    _Float16* Kh = Ql + ARRN;
    _Float16* Kl = Kh + ARRN;
    float* kn = (float*)(Kl + ARRN);          // 8192 f32
    unsigned long long* fidx64 = (unsigned long long*)(kn + 8192);   // 8192 u64

    dim3 gp(ARRN / 8 / 256, 2);
    k_prep<<<gp, 256, 0, stream>>>(query, key, Qh, Ql, Kh, Kl);
    k_kn<<<2048, 256, 0, stream>>>(key, kn, fidx64);
    dim3 g(64, 64);
    k_nn<<<g, 256, 0, stream>>>(Qh, Ql, Kh, Kl, kn, fidx64);
    k_fold<<<108, 256, 0, stream>>>(value, fidx64, out);
}

// Round 5
// 164.136 us; speedup vs baseline: 2.1519x; 1.2398x over previous
//
#include <hip/hip_runtime.h>

// TorchPatchNN: unfold(7x7) -> NN argmin over 8100 keys (D=147) -> gather value -> fold mean.
// Round 5: latency attack on k_nn (R4 was 22% MfmaUtil = idle 78%):
//  - XCD-aware swizzle: blockIdx%8 -> XCD rectangle of 16qt x 32kt => per-XCD operand
//    working set 3.84 MB fits the 4 MiB L2 (was ~10.5 MB falling to L3).
//  - Double-buffered one-barrier K-loop: prefetch chunk c+1 via global_load_lds into the
//    other 32 KiB buffer while MFMAing chunk c => vmcnt drain at the barrier has full cover.
//  - Reduction scan stride 32 -> 33: R4's 3.36e7 bank conflicts were the 64-lanes-same-bank
//    scan reads, not the frag path.
//  - k_kn fused into k_prep (one fewer launch).
// Numerics unchanged (fp16 h + 2^-11*l split, 3 MFMA passes, tie-aware packed-u64 atomicMin).

#define NQ 8100
#define NK 8100
#define DD 147
#define HO 90
#define IMG 96
#define NCH 5                 // K chunks of 32 (160 padded K)
#define CST 262144            // f16 per chunk plane: 512 groups x 512
#define ARRN (NCH * CST)      // f16 per array

typedef _Float16 half8 __attribute__((ext_vector_type(8)));
typedef float f32x4 __attribute__((ext_vector_type(4)));

__device__ __forceinline__ void gld16(const _Float16* g, _Float16* l) {
    __builtin_amdgcn_global_load_lds(
        (const __attribute__((address_space(1))) unsigned int*)g,
        (__attribute__((address_space(3))) unsigned int*)l, 16, 0, 0);
}

// ---------------- prep: split Q/K into fp16 hi/lo (frag order) + key norms + init ---------
__global__ void k_prep(const float* __restrict__ query, const float* __restrict__ key,
                       _Float16* __restrict__ Qh, _Float16* __restrict__ Ql,
                       _Float16* __restrict__ Kh, _Float16* __restrict__ Kl,
                       float* __restrict__ kn, unsigned long long* __restrict__ fidx64) {
    const int bx = blockIdx.x;
    const bool isK = (blockIdx.y != 0);

    if (bx >= 640) {                      // fused k_kn region: 128 blocks on y==1
        if (!isK) return;
        int wave = threadIdx.x >> 6, lane = threadIdx.x & 63;
        int kb = ((bx - 640) * 4 + wave) * 16;
        for (int r = 0; r < 16; ++r) {
            int k = kb + r;
            float s = 0.f;
            if (k < NK)
                for (int d = lane; d < DD; d += 64) {
                    float v = key[k * DD + d];
                    s += v * v;
                }
#pragma unroll
            for (int off = 32; off; off >>= 1) s += __shfl_down(s, off, 64);
            if (lane == 0) {
                kn[k] = (k < NK) ? s : 1e30f;
                fidx64[k] = 0xFFFFFFFFFFFFFFFFull;   // ws re-poisoned every launch
            }
        }
        return;
    }

    int t = bx * 256 + threadIdx.x;             // 0 .. 163839 (ARRN/8)
    int c = t >> 15;                            // chunk
    int rem = t & 32767;                        // g*64 + lane
    int col = ((rem >> 6) << 4) + (rem & 15);   // g*16 + l15
    int quad = (rem >> 4) & 3;
    int kbase = c * 32 + quad * 8;

    float v[8];
#pragma unroll
    for (int j = 0; j < 8; ++j) {
        int k = kbase + j;
        float x = 0.f;
        if (k < DD && col < NQ) {
            if (isK) {
                x = key[col * DD + k];
            } else {
                int c3 = k / 49, r2 = k - 49 * c3;
                int rr = r2 / 7, ss = r2 - 7 * rr;
                int y = col / HO, xx = col - HO * y;
                x = query[(c3 * IMG + y + rr) * IMG + xx + ss];
            }
        }
        v[j] = x;
    }
    half8 h8, l8;
#pragma unroll
    for (int j = 0; j < 8; ++j) {
        _Float16 h = (_Float16)v[j];
        h8[j] = h;
        l8[j] = (_Float16)((v[j] - (float)h) * 2048.0f);
    }
    if (isK) {
        *(half8*)(Kh + t * 8) = h8;
        *(half8*)(Kl + t * 8) = l8;
    } else {
        *(half8*)(Qh + t * 8) = h8;
        *(half8*)(Ql + t * 8) = l8;
    }
}

// ---------------- main: split-f16 MFMA Q.K^T + fused argmin ----------------
__launch_bounds__(256, 2)
__global__ void k_nn(const _Float16* __restrict__ Qh, const _Float16* __restrict__ Ql,
                     const _Float16* __restrict__ Kh, const _Float16* __restrict__ Kl,
                     const float* __restrict__ kn, unsigned long long* __restrict__ out) {
    __shared__ __align__(16) char smem[65536];   // 2 x 32 KiB stage buffers (aliased epilogue)
    _Float16* sbase = (_Float16*)smem;

    const int tid = (int)threadIdx.x;
    const int wave = tid >> 6, lane = tid & 63;
    const int l15 = lane & 15, quad = lane >> 4;

    // XCD-aware swizzle: blockIdx%8 == XCD (round-robin heuristic). Each XCD gets a
    // 16qt x 32kt rectangle => Q 1.28 MB + K 2.56 MB = 3.84 MB <= 4 MiB L2.
    const int b = (int)blockIdx.x;
    const int xcd = b & 7;
    const int i = b >> 3;                         // 0..511 within XCD
    const int qt = (xcd >> 1) * 16 + (i & 15);
    const int kt = (xcd & 1) * 32 + (i >> 4);

    const int mbase = (wave >> 1) * 64;           // wave tile: 64x64 within 128x128
    const int nbase = (wave & 1) * 64;
    const int q0 = qt * 128, n0 = kt * 128;

    // per-wave staging source: wave 0->Qh,1->Ql,2->Kh,3->Kl
    const _Float16* gsrc = (wave == 0) ? Qh : (wave == 1) ? Ql : (wave == 2) ? Kh : Kl;
    const int gbase = ((wave < 2) ? qt : kt) * 8;
    const _Float16* gp0 = gsrc + gbase * 512 + lane * 8;
    _Float16* ldst0 = sbase + wave * 4096 + lane * 8;

    f32x4 acc0[4][4], acc1[4][4];
#pragma unroll
    for (int ii = 0; ii < 4; ++ii)
#pragma unroll
        for (int j = 0; j < 4; ++j) {
            acc0[ii][j] = (f32x4)0.f;
            acc1[ii][j] = (f32x4)0.f;
        }

    const int agrp = (mbase >> 4);
    const int bgrp = (nbase >> 4);

    // preamble: stage chunk 0 into buffer 0
#pragma unroll
    for (int grp = 0; grp < 8; ++grp)
        gld16(gp0 + grp * 512, ldst0 + grp * 512);

#pragma unroll
    for (int c = 0; c < NCH; ++c) {
        __syncthreads();   // drains vmcnt -> buf[c&1] ready for all waves
        if (c + 1 < NCH) { // prefetch next chunk into the other buffer (full compute cover)
            const _Float16* gp = gp0 + (c + 1) * CST;
            _Float16* ld = ldst0 + ((c + 1) & 1) * 16384;
#pragma unroll
            for (int grp = 0; grp < 8; ++grp)
                gld16(gp + grp * 512, ld + grp * 512);
        }

        const _Float16* sQh = sbase + (c & 1) * 16384;
        const _Float16* sQl = sQh + 4096;
        const _Float16* sKh = sQh + 8192;
        const _Float16* sKl = sQh + 12288;

        half8 ah[4], al[4];
#pragma unroll
        for (int mt = 0; mt < 4; ++mt) {
            int aoff = (agrp + mt) * 512 + lane * 8;
            ah[mt] = *(const half8*)(sQh + aoff);
            al[mt] = *(const half8*)(sQl + aoff);
        }
#pragma unroll
        for (int nt = 0; nt < 4; ++nt) {
            int boff = (bgrp + nt) * 512 + lane * 8;
            half8 bh = *(const half8*)(sKh + boff);
            half8 bl = *(const half8*)(sKl + boff);
#pragma unroll
            for (int mt = 0; mt < 4; ++mt) {
                acc0[mt][nt] = __builtin_amdgcn_mfma_f32_16x16x32_f16(ah[mt], bh, acc0[mt][nt], 0, 0, 0);
                acc1[mt][nt] = __builtin_amdgcn_mfma_f32_16x16x32_f16(ah[mt], bl, acc1[mt][nt], 0, 0, 0);
                acc1[mt][nt] = __builtin_amdgcn_mfma_f32_16x16x32_f16(al[mt], bh, acc1[mt][nt], 0, 0, 0);
            }
        }
    }

    // epilogue: dist = kn - 2*(acc0 + acc1/2048); per-lane argmin over its 4 columns
    float knv[4];
    int nglob[4];
#pragma unroll
    for (int nt = 0; nt < 4; ++nt) {
        nglob[nt] = n0 + nbase + nt * 16 + l15;
        knv[nt] = kn[nglob[nt]];
    }
    __syncthreads();   // done with staging LDS; reuse for reduction
    float* redv = (float*)smem;            // [128][33] f32, pad stride kills bank conflicts
    int* redi = (int*)(smem + 17408);      // [128][33] i32

#pragma unroll
    for (int mt = 0; mt < 4; ++mt)
#pragma unroll
        for (int r = 0; r < 4; ++r) {
            float bv = 1e38f;
            int bn = 0x7fffffff;
#pragma unroll
            for (int nt = 0; nt < 4; ++nt) {   // ascending n within lane -> strict < ok
                float d = knv[nt] - 2.0f * (acc0[mt][nt][r] + acc1[mt][nt][r] * (1.0f / 2048.0f));
                if (d < bv) { bv = d; bn = nglob[nt]; }
            }
            int m = mbase + mt * 16 + quad * 4 + r;        // C layout: row = quad*4 + reg
            int cidx = (nbase >> 2) + l15;                 // 0..31
            redv[m * 33 + cidx] = bv;
            redi[m * 33 + cidx] = bn;
        }
    __syncthreads();

    if (tid < 128) {
        float bv = 1e38f;
        int bn = 0x7fffffff;
        for (int t2 = 0; t2 < 32; ++t2) {     // tie-aware compare (lanes interleave n)
            float v = redv[tid * 33 + t2];
            int n = redi[tid * 33 + t2];
            if (v < bv || (v == bv && n < bn)) { bv = v; bn = n; }
        }
        unsigned u = __float_as_uint(bv);
        u = (u & 0x80000000u) ? ~u : (u | 0x80000000u);   // order-preserving map
        unsigned long long pk = ((unsigned long long)u << 32) | (unsigned)bn;
        atomicMin(&out[q0 + tid], pk);
    }
}

// ---------------- gather + fold (overlap-add mean) ----------------
__global__ void k_fold(const float* __restrict__ value,
                       const unsigned long long* __restrict__ fidx64,
                       float* __restrict__ out) {
    int t = blockIdx.x * 256 + threadIdx.x;   // 3*96*96 = 27648
    if (t >= 3 * IMG * IMG) return;
    int c = t / (IMG * IMG);
    int rem = t % (IMG * IMG);
    int Y = rem / IMG, X = rem % IMG;
    int i0 = max(0, Y - (HO - 1)), i1 = min(6, Y);
    int j0 = max(0, X - (HO - 1)), j1 = min(6, X);
    float s = 0.f;
    for (int i = i0; i <= i1; ++i)
        for (int j = j0; j <= j1; ++j) {
            int p = (Y - i) * HO + (X - j);
            int row = (int)(fidx64[p] & 0xFFFFFFFFull);
            s += value[row * DD + c * 49 + i * 7 + j];
        }
    float cnt = (float)((i1 - i0 + 1) * (j1 - j0 + 1));
    out[t] = s / cnt;
}

extern "C" void kernel_launch(void* const* d_in, const int* in_sizes, int n_in,
                              void* d_out, int out_size, void* d_ws, size_t ws_size,
                              hipStream_t stream) {
    const float* query = (const float*)d_in[0];
    const float* key   = (const float*)d_in[1];
    const float* value = (const float*)d_in[2];
    float* out = (float*)d_out;

    _Float16* Qh = (_Float16*)d_ws;           // ARRN f16 each
    _Float16* Ql = Qh + ARRN;
    _Float16* Kh = Ql + ARRN;
    _Float16* Kl = Kh + ARRN;
    float* kn = (float*)(Kl + ARRN);          // 8192 f32
    unsigned long long* fidx64 = (unsigned long long*)(kn + 8192);   // 8192 u64

    dim3 gp(768, 2);   // 640 split blocks + 128 fused-kn blocks (y==1)
    k_prep<<<gp, 256, 0, stream>>>(query, key, Qh, Ql, Kh, Kl, kn, fidx64);
    k_nn<<<4096, 256, 0, stream>>>(Qh, Ql, Kh, Kl, kn, fidx64);
    k_fold<<<108, 256, 0, stream>>>(value, fidx64, out);
}